// Round 1
// baseline (805.464 us; speedup 1.0000x reference)
//
#include <hip/hip_runtime.h>
#include <hip/hip_bf16.h>

// ---------------------------------------------------------------------------
// EncoderLayer on MI355X (gfx950).
// Pipeline: cast/transposes -> QKV gemms (bf16 MFMA) -> flash attention ->
//           Wo gemm -> LN1 -> FF1(relu) -> FF2 -> LN2 -> d_out (fp32).
// All matmuls: m97-style 128x128 tile, global_load_lds(16B), BK=32,
// mfma_f32_16x16x32_bf16, XOR chunk swizzle in LDS.
// Workspace requirement: 184 MB.
// ---------------------------------------------------------------------------

#define DM    1024
#define DFF   4096
#define NH    16
#define HD    64
#define BATCH 4
#define SEQ   2048
#define TOK   (BATCH * SEQ)   // 8192

typedef __attribute__((ext_vector_type(8))) __bf16 bf16x8;
typedef __attribute__((ext_vector_type(4))) float f32x4;
typedef __attribute__((ext_vector_type(4))) unsigned short u16x4;
typedef __attribute__((ext_vector_type(8))) unsigned short u16x8;

typedef const __attribute__((address_space(1))) unsigned int* gas1_t;
typedef __attribute__((address_space(3))) unsigned int* las3_t;

__device__ __forceinline__ void gl_lds16(const void* g, void* l) {
  // async global->LDS, 16B per lane; LDS dest = wave-uniform base + lane*16
  __builtin_amdgcn_global_load_lds((gas1_t)g, (las3_t)l, 16, 0, 0);
}

__device__ __forceinline__ unsigned short f2bu(float x) {
  return __builtin_bit_cast(unsigned short, __float2bfloat16(x));
}

// ---------------------------------------------------------------------------
// cast fp32 -> bf16 (vectorized x4)
// ---------------------------------------------------------------------------
__global__ __launch_bounds__(256) void cast_bf16(
    const float* __restrict__ in, unsigned short* __restrict__ out, int n4) {
  int i = blockIdx.x * 256 + threadIdx.x;
  if (i >= n4) return;
  float4 v = ((const float4*)in)[i];
  u16x4 o = {f2bu(v.x), f2bu(v.y), f2bu(v.z), f2bu(v.w)};
  ((u16x4*)out)[i] = o;
}

// ---------------------------------------------------------------------------
// out[n][k] = bf16(in[k][n])   (LDS-tiled transpose, block (32,8))
// ---------------------------------------------------------------------------
__global__ __launch_bounds__(256) void transpose_cast(
    const float* __restrict__ in, unsigned short* __restrict__ out, int K, int N) {
  __shared__ float tile[32][33];
  int n0 = blockIdx.x * 32, k0 = blockIdx.y * 32;
  int tx = threadIdx.x, ty = threadIdx.y;
#pragma unroll
  for (int i = 0; i < 4; ++i)
    tile[ty + 8 * i][tx] = in[(size_t)(k0 + ty + 8 * i) * N + n0 + tx];
  __syncthreads();
#pragma unroll
  for (int i = 0; i < 4; ++i)
    out[(size_t)(n0 + ty + 8 * i) * K + k0 + tx] = f2bu(tile[tx][ty + 8 * i]);
}

// ---------------------------------------------------------------------------
// C[M,N] = epilogue(A[M,K] @ Bt[N,K]^T + bias) ; A,Bt bf16, acc fp32.
// 128x128 tile / block(256) = 4 waves in 2x2, each wave 64x64 (4x4 MFMA).
// epilogue: val = alpha*(acc+bias[col]); optional relu; fp32 or bf16 store.
// ---------------------------------------------------------------------------
__global__ __launch_bounds__(256) void gemm_bt(
    const unsigned short* __restrict__ A, const unsigned short* __restrict__ Bt,
    const float* __restrict__ bias, void* __restrict__ Cout,
    int M, int N, int K, float alpha, int relu, int ofp32) {
  __shared__ unsigned short As[128 * 32];  // [row m][k 0..31], chunk-swizzled
  __shared__ unsigned short Bs[128 * 32];  // [row n][k 0..31], chunk-swizzled
  const int tid = threadIdx.x, lane = tid & 63, w = tid >> 6;
  const int l15 = lane & 15, quad = lane >> 4;
  const int m0 = blockIdx.y * 128, n0 = blockIdx.x * 128;
  const int wr = w >> 1, wc = w & 1;

  f32x4 acc[4][4];
#pragma unroll
  for (int mi = 0; mi < 4; ++mi)
#pragma unroll
    for (int ni = 0; ni < 4; ++ni) acc[mi][ni] = {0.f, 0.f, 0.f, 0.f};

  // staging decode: flat 16B-chunk id -> (row, swizzled k-chunk)
  int rowS[2], colS[2];
#pragma unroll
  for (int i = 0; i < 2; ++i) {
    int f16 = (i * 4 + w) * 64 + lane;      // 0..511
    rowS[i] = f16 >> 2;                     // 4 chunks per 32-elem row
    colS[i] = ((f16 & 3) ^ (rowS[i] & 3)) * 8;  // element offset of k-chunk
  }
  const int swz = (quad ^ (l15 & 3)) * 16;  // reader: byte offset of chunk

  for (int kb = 0; kb < K; kb += 32) {
#pragma unroll
    for (int i = 0; i < 2; ++i) {
      gl_lds16(A + (size_t)(m0 + rowS[i]) * K + kb + colS[i],
               (char*)As + (size_t)((i * 4 + w) * 1024));
      gl_lds16(Bt + (size_t)(n0 + rowS[i]) * K + kb + colS[i],
               (char*)Bs + (size_t)((i * 4 + w) * 1024));
    }
    __syncthreads();  // drains vmcnt for global_load_lds
    bf16x8 aF[4], bF[4];
#pragma unroll
    for (int t = 0; t < 4; ++t) {
      aF[t] = *(const bf16x8*)((const char*)As + (wr * 64 + t * 16 + l15) * 64 + swz);
      bF[t] = *(const bf16x8*)((const char*)Bs + (wc * 64 + t * 16 + l15) * 64 + swz);
    }
#pragma unroll
    for (int mi = 0; mi < 4; ++mi)
#pragma unroll
      for (int ni = 0; ni < 4; ++ni)
        acc[mi][ni] = __builtin_amdgcn_mfma_f32_16x16x32_bf16(
            aF[mi], bF[ni], acc[mi][ni], 0, 0, 0);
    __syncthreads();
  }

#pragma unroll
  for (int ni = 0; ni < 4; ++ni) {
    int col = n0 + wc * 64 + ni * 16 + l15;
    float bvv = bias[col];
#pragma unroll
    for (int mi = 0; mi < 4; ++mi) {
      int rbase = m0 + wr * 64 + mi * 16 + quad * 4;
#pragma unroll
      for (int r = 0; r < 4; ++r) {
        float val = alpha * (acc[mi][ni][r] + bvv);
        if (relu) val = fmaxf(val, 0.f);
        size_t idx = (size_t)(rbase + r) * N + col;
        if (ofp32) ((float*)Cout)[idx] = val;
        else ((unsigned short*)Cout)[idx] = f2bu(val);
      }
    }
  }
}

// ---------------------------------------------------------------------------
// Flash attention. grid = (SEQ/128, BATCH*NH), block = 256 (4 waves).
// Q pre-scaled by 1/sqrt(HD) in its GEMM. BQ=128 q rows/block, BKV=64.
// S = Q K^T  (gemm_bt: A=Qt rows q, Bt=Kt rows kv)
// O^T = V^T P^T (gemm_bt: A=Vt rows d, Bt=Pt rows q)  -> avoids P relayout.
// LDS 49KB -> 3 blocks/CU. XOR chunk swizzle on all tiles.
// ---------------------------------------------------------------------------
__global__ __launch_bounds__(256) void attn_kernel(
    const unsigned short* __restrict__ Q, const unsigned short* __restrict__ K,
    const unsigned short* __restrict__ V, unsigned short* __restrict__ O) {
  __shared__ unsigned short Qt[128 * 64];  // [q][d]   16KB
  __shared__ unsigned short Kt[64 * 64];   // [kv][d]   8KB
  __shared__ unsigned short Vt[64 * 64];   // [d][kv]   8KB (V^T)
  __shared__ unsigned short Pt[128 * 64];  // [q][kv]  16KB
  __shared__ float redA[128];
  __shared__ float redL[128];

  const int tid = threadIdx.x, lane = tid & 63, w = tid >> 6;
  const int l15 = lane & 15, quad = lane >> 4;
  const int q0 = blockIdx.x * 128;
  const int bh = blockIdx.y;
  const size_t tokbase = (size_t)(bh >> 4) * SEQ;
  const int cbase = (bh & 15) * HD;

  // stage Q tile (1024 chunks of 16B)
#pragma unroll
  for (int i = 0; i < 4; ++i) {
    int f16 = (i * 4 + w) * 64 + lane;
    int row = f16 >> 3, cc = (f16 & 7) ^ (row & 7);
    gl_lds16(Q + (tokbase + q0 + row) * DM + cbase + cc * 8,
             (char*)Qt + (size_t)(i * 4 + w) * 1024);
  }

  float m_run[2][4], l_run[2][4];
#pragma unroll
  for (int ti = 0; ti < 2; ++ti)
#pragma unroll
    for (int r = 0; r < 4; ++r) { m_run[ti][r] = -3.0e38f; l_run[ti][r] = 0.f; }
  f32x4 Oacc[4][2];
#pragma unroll
  for (int dt = 0; dt < 4; ++dt)
#pragma unroll
    for (int qt = 0; qt < 2; ++qt) Oacc[dt][qt] = {0.f, 0.f, 0.f, 0.f};

  for (int j = 0; j < SEQ / 64; ++j) {
    const int kv0 = j * 64;
    __syncthreads();  // previous iteration's consumers of Kt/Vt/Pt are done
    // stage K tile (512 chunks)
#pragma unroll
    for (int i = 0; i < 2; ++i) {
      int f16 = (i * 4 + w) * 64 + lane;
      int row = f16 >> 3, cc = (f16 & 7) ^ (row & 7);
      gl_lds16(K + (tokbase + kv0 + row) * DM + cbase + cc * 8,
               (char*)Kt + (size_t)(i * 4 + w) * 1024);
    }
    // stage V transposed: wave w covers d-chunks {2w, 2w+1}, lane = kv
#pragma unroll
    for (int i = 0; i < 2; ++i) {
      int c = w * 2 + i;
      int kv = lane;
      float4 fv = *(const float4*)(V + (tokbase + kv0 + kv) * DM + cbase + c * 8);
      u16x8 uv = __builtin_bit_cast(u16x8, fv);
#pragma unroll
      for (int dj = 0; dj < 8; ++dj) {
        int d = c * 8 + dj;
        Vt[d * 64 + (((kv >> 3) ^ dj) * 8) + (kv & 7)] = uv[dj];
      }
    }
    __syncthreads();  // Kt/Vt (and on j==0, Qt) ready

    // ---- S = Q K^T ---- wave w owns q rows [w*32, w*32+32)
    f32x4 S[2][4];
#pragma unroll
    for (int ti = 0; ti < 2; ++ti)
#pragma unroll
      for (int cj = 0; cj < 4; ++cj) S[ti][cj] = {0.f, 0.f, 0.f, 0.f};
#pragma unroll
    for (int kk = 0; kk < 2; ++kk) {
      int swz = ((kk * 4 + quad) ^ (l15 & 7)) * 8;
      bf16x8 aQ[2];
#pragma unroll
      for (int ti = 0; ti < 2; ++ti)
        aQ[ti] = *(const bf16x8*)(Qt + (w * 32 + ti * 16 + l15) * 64 + swz);
#pragma unroll
      for (int cj = 0; cj < 4; ++cj) {
        bf16x8 bK = *(const bf16x8*)(Kt + (cj * 16 + l15) * 64 + swz);
        S[0][cj] = __builtin_amdgcn_mfma_f32_16x16x32_bf16(aQ[0], bK, S[0][cj], 0, 0, 0);
        S[1][cj] = __builtin_amdgcn_mfma_f32_16x16x32_bf16(aQ[1], bK, S[1][cj], 0, 0, 0);
      }
    }

    // ---- online softmax (rows live in this wave; C-layout row=quad*4+r) ----
#pragma unroll
    for (int ti = 0; ti < 2; ++ti) {
#pragma unroll
      for (int r = 0; r < 4; ++r) {
        float mx = S[ti][0][r];
#pragma unroll
        for (int cj = 1; cj < 4; ++cj) mx = fmaxf(mx, S[ti][cj][r]);
        mx = fmaxf(mx, __shfl_xor(mx, 1));
        mx = fmaxf(mx, __shfl_xor(mx, 2));
        mx = fmaxf(mx, __shfl_xor(mx, 4));
        mx = fmaxf(mx, __shfl_xor(mx, 8));
        float mn = fmaxf(m_run[ti][r], mx);
        float al = __expf(m_run[ti][r] - mn);
        m_run[ti][r] = mn;
        int qrow = w * 32 + ti * 16 + quad * 4 + r;
        float rs = 0.f;
#pragma unroll
        for (int cj = 0; cj < 4; ++cj) {
          float p = __expf(S[ti][cj][r] - mn);
          rs += p;
          int kv = cj * 16 + l15;
          Pt[qrow * 64 + (((kv >> 3) ^ (qrow & 7)) * 8) + (kv & 7)] = f2bu(p);
        }
        rs += __shfl_xor(rs, 1);
        rs += __shfl_xor(rs, 2);
        rs += __shfl_xor(rs, 4);
        rs += __shfl_xor(rs, 8);
        l_run[ti][r] = l_run[ti][r] * al + rs;
        if (l15 == 0) redA[qrow] = al;
      }
    }
    // Pt / redA produced & consumed within the same wave: per-wave DS ordering
    // makes them visible without a barrier.

    float aq0 = redA[w * 32 + l15];
    float aq1 = redA[w * 32 + 16 + l15];
#pragma unroll
    for (int dt = 0; dt < 4; ++dt) {
      Oacc[dt][0] *= aq0;
      Oacc[dt][1] *= aq1;
    }
    // ---- O^T += V^T P^T ----
#pragma unroll
    for (int kk = 0; kk < 2; ++kk) {
      int swz = ((kk * 4 + quad) ^ (l15 & 7)) * 8;
      bf16x8 aV[4];
#pragma unroll
      for (int dt = 0; dt < 4; ++dt)
        aV[dt] = *(const bf16x8*)(Vt + (dt * 16 + l15) * 64 + swz);
#pragma unroll
      for (int qt = 0; qt < 2; ++qt) {
        bf16x8 bP = *(const bf16x8*)(Pt + (w * 32 + qt * 16 + l15) * 64 + swz);
#pragma unroll
        for (int dt = 0; dt < 4; ++dt)
          Oacc[dt][qt] = __builtin_amdgcn_mfma_f32_16x16x32_bf16(
              aV[dt], bP, Oacc[dt][qt], 0, 0, 0);
      }
    }
  }

  // epilogue: divide by row sums, store O (O^T C-layout: row=d, col=q)
#pragma unroll
  for (int ti = 0; ti < 2; ++ti)
#pragma unroll
    for (int r = 0; r < 4; ++r)
      if (l15 == 0) redL[w * 32 + ti * 16 + quad * 4 + r] = l_run[ti][r];
  float li0 = 1.f / redL[w * 32 + l15];
  float li1 = 1.f / redL[w * 32 + 16 + l15];
#pragma unroll
  for (int qt = 0; qt < 2; ++qt) {
    float li = qt ? li1 : li0;
    int q = w * 32 + qt * 16 + l15;
#pragma unroll
    for (int dt = 0; dt < 4; ++dt)
#pragma unroll
      for (int r = 0; r < 4; ++r) {
        int d = dt * 16 + quad * 4 + r;
        O[(tokbase + q0 + q) * DM + cbase + d] = f2bu(Oacc[dt][qt][r] * li);
      }
  }
}

// ---------------------------------------------------------------------------
// row-wise: s = base + delta; LN(s)*gamma+beta -> outf (fp32), outb (bf16 opt)
// one block per row, 256 threads x 4 elems.
// ---------------------------------------------------------------------------
__global__ __launch_bounds__(256) void ln_res(
    const float* __restrict__ base, const float* __restrict__ delta,
    const float* __restrict__ gamma, const float* __restrict__ beta,
    float* __restrict__ outf, unsigned short* __restrict__ outb) {
  __shared__ float red[8];
  const int row = blockIdx.x, tid = threadIdx.x;
  const size_t rb = (size_t)row * DM;
  float4 xv = ((const float4*)(base + rb))[tid];
  float4 dv = ((const float4*)(delta + rb))[tid];
  float s0 = xv.x + dv.x, s1 = xv.y + dv.y, s2 = xv.z + dv.z, s3 = xv.w + dv.w;
  float t = s0 + s1 + s2 + s3;
#pragma unroll
  for (int m = 1; m < 64; m <<= 1) t += __shfl_xor(t, m);
  if ((tid & 63) == 0) red[tid >> 6] = t;
  __syncthreads();
  float mu = (red[0] + red[1] + red[2] + red[3]) * (1.0f / DM);
  float d0 = s0 - mu, d1 = s1 - mu, d2 = s2 - mu, d3 = s3 - mu;
  float v = d0 * d0 + d1 * d1 + d2 * d2 + d3 * d3;
#pragma unroll
  for (int m = 1; m < 64; m <<= 1) v += __shfl_xor(v, m);
  if ((tid & 63) == 0) red[4 + (tid >> 6)] = v;
  __syncthreads();
  float var = (red[4] + red[5] + red[6] + red[7]) * (1.0f / DM);
  float rs = rsqrtf(var + 1e-5f);
  float4 gv = ((const float4*)gamma)[tid];
  float4 bv = ((const float4*)beta)[tid];
  float o0 = d0 * rs * gv.x + bv.x;
  float o1 = d1 * rs * gv.y + bv.y;
  float o2 = d2 * rs * gv.z + bv.z;
  float o3 = d3 * rs * gv.w + bv.w;
  float4 ov = {o0, o1, o2, o3};
  ((float4*)(outf + rb))[tid] = ov;
  if (outb) {
    u16x4 ob = {f2bu(o0), f2bu(o1), f2bu(o2), f2bu(o3)};
    ((u16x4*)(outb + rb))[tid] = ob;
  }
}

// ---------------------------------------------------------------------------
extern "C" void kernel_launch(void* const* d_in, const int* in_sizes, int n_in,
                              void* d_out, int out_size, void* d_ws, size_t ws_size,
                              hipStream_t stream) {
  const float* x   = (const float*)d_in[0];
  const float* Wq  = (const float*)d_in[1];  const float* bq  = (const float*)d_in[2];
  const float* Wk  = (const float*)d_in[3];  const float* bk  = (const float*)d_in[4];
  const float* Wv  = (const float*)d_in[5];  const float* bvv = (const float*)d_in[6];
  const float* Wo  = (const float*)d_in[7];  const float* bo  = (const float*)d_in[8];
  const float* W1  = (const float*)d_in[9];  const float* b1  = (const float*)d_in[10];
  const float* W2  = (const float*)d_in[11]; const float* b2  = (const float*)d_in[12];
  const float* g1  = (const float*)d_in[13]; const float* be1 = (const float*)d_in[14];
  const float* g2  = (const float*)d_in[15]; const float* be2 = (const float*)d_in[16];

  char* ws = (char*)d_ws;
  const size_t MB = 1ull << 20;
  unsigned short* xb  = (unsigned short*)(ws + 0 * MB);    // 16MB
  unsigned short* wqT = (unsigned short*)(ws + 16 * MB);   // 2MB
  unsigned short* wkT = (unsigned short*)(ws + 18 * MB);   // 2MB
  unsigned short* wvT = (unsigned short*)(ws + 20 * MB);   // 2MB
  unsigned short* woT = (unsigned short*)(ws + 22 * MB);   // 2MB
  unsigned short* w1T = (unsigned short*)(ws + 24 * MB);   // 8MB
  unsigned short* w2T = (unsigned short*)(ws + 32 * MB);   // 8MB
  unsigned short* Qb  = (unsigned short*)(ws + 40 * MB);   // 16MB
  unsigned short* Kb  = (unsigned short*)(ws + 56 * MB);   // 16MB
  unsigned short* Vb  = (unsigned short*)(ws + 72 * MB);   // 16MB
  unsigned short* aO  = (unsigned short*)(ws + 88 * MB);   // 16MB
  float*          prj = (float*)(ws + 104 * MB);           // 32MB fp32
  float*          h   = (float*)(ws + 136 * MB);           // 32MB fp32
  unsigned short* hb  = (unsigned short*)(ws + 168 * MB);  // 16MB
  unsigned short* ffm = (unsigned short*)(ws + 40 * MB);   // 64MB, alias Q/K/V/aO (dead)
  float*          ffo = (float*)(ws + 104 * MB);           // 32MB, alias prj (dead)
  (void)ws_size; (void)in_sizes; (void)n_in; (void)out_size;

  // prep: casts + weight transposes (B^T bf16)
  cast_bf16<<<TOK * DM / 4 / 256, 256, 0, stream>>>(x, xb, TOK * DM / 4);
  transpose_cast<<<dim3(DM / 32, DM / 32), dim3(32, 8), 0, stream>>>(Wq, wqT, DM, DM);
  transpose_cast<<<dim3(DM / 32, DM / 32), dim3(32, 8), 0, stream>>>(Wk, wkT, DM, DM);
  transpose_cast<<<dim3(DM / 32, DM / 32), dim3(32, 8), 0, stream>>>(Wv, wvT, DM, DM);
  transpose_cast<<<dim3(DM / 32, DM / 32), dim3(32, 8), 0, stream>>>(Wo, woT, DM, DM);
  transpose_cast<<<dim3(DFF / 32, DM / 32), dim3(32, 8), 0, stream>>>(W1, w1T, DM, DFF);
  transpose_cast<<<dim3(DM / 32, DFF / 32), dim3(32, 8), 0, stream>>>(W2, w2T, DFF, DM);

  // QKV projections (alpha=1/sqrt(HD) folded into Q)
  gemm_bt<<<dim3(DM / 128, TOK / 128), 256, 0, stream>>>(xb, wqT, bq, Qb, TOK, DM, DM, 0.125f, 0, 0);
  gemm_bt<<<dim3(DM / 128, TOK / 128), 256, 0, stream>>>(xb, wkT, bk, Kb, TOK, DM, DM, 1.0f, 0, 0);
  gemm_bt<<<dim3(DM / 128, TOK / 128), 256, 0, stream>>>(xb, wvT, bvv, Vb, TOK, DM, DM, 1.0f, 0, 0);

  // attention
  attn_kernel<<<dim3(SEQ / 128, BATCH * NH), 256, 0, stream>>>(Qb, Kb, Vb, aO);

  // output projection (fp32 out for residual precision)
  gemm_bt<<<dim3(DM / 128, TOK / 128), 256, 0, stream>>>(aO, woT, bo, prj, TOK, DM, DM, 1.0f, 0, 1);
  // LN1: h = LN(x + prj) -> fp32 h + bf16 hb
  ln_res<<<TOK, 256, 0, stream>>>(x, prj, g1, be1, h, hb);

  // FF
  gemm_bt<<<dim3(DFF / 128, TOK / 128), 256, 0, stream>>>(hb, w1T, b1, ffm, TOK, DFF, DM, 1.0f, 1, 0);
  gemm_bt<<<dim3(DM / 128, TOK / 128), 256, 0, stream>>>(ffm, w2T, b2, ffo, TOK, DM, DFF, 1.0f, 0, 1);

  // LN2 -> d_out (fp32)
  ln_res<<<TOK, 256, 0, stream>>>(h, ffo, g2, be2, (float*)d_out, nullptr);
}

// Round 2
// 640.343 us; speedup vs baseline: 1.2579x; 1.2579x over previous
//
#include <hip/hip_runtime.h>
#include <hip/hip_bf16.h>

// ---------------------------------------------------------------------------
// EncoderLayer on MI355X (gfx950), round 2.
// Changes vs R1: fused QKV gemm (V written transposed per head), attention
// recomputed as S^T = K Q^T so softmax is in-register (2 shfl vs 64), Q held
// in registers (no Qt LDS), BQ=64 (25KB LDS -> ~4 blocks/CU).
// Workspace: 184 MB.
// ---------------------------------------------------------------------------

#define DM    1024
#define DFF   4096
#define NH    16
#define HD    64
#define BATCH 4
#define SEQ   2048
#define TOK   (BATCH * SEQ)   // 8192

typedef __attribute__((ext_vector_type(8))) __bf16 bf16x8;
typedef __attribute__((ext_vector_type(4))) float f32x4;
typedef __attribute__((ext_vector_type(4))) unsigned short u16x4;

typedef const __attribute__((address_space(1))) unsigned int* gas1_t;
typedef __attribute__((address_space(3))) unsigned int* las3_t;

__device__ __forceinline__ void gl_lds16(const void* g, void* l) {
  // async global->LDS, 16B per lane; LDS dest = wave-uniform base + lane*16
  __builtin_amdgcn_global_load_lds((gas1_t)g, (las3_t)l, 16, 0, 0);
}

__device__ __forceinline__ unsigned short f2bu(float x) {
  return __builtin_bit_cast(unsigned short, __float2bfloat16(x));
}

// ---------------------------------------------------------------------------
// cast fp32 -> bf16 (vectorized x4)
// ---------------------------------------------------------------------------
__global__ __launch_bounds__(256) void cast_bf16(
    const float* __restrict__ in, unsigned short* __restrict__ out, int n4) {
  int i = blockIdx.x * 256 + threadIdx.x;
  if (i >= n4) return;
  float4 v = ((const float4*)in)[i];
  u16x4 o = {f2bu(v.x), f2bu(v.y), f2bu(v.z), f2bu(v.w)};
  ((u16x4*)out)[i] = o;
}

// ---------------------------------------------------------------------------
// out[n][k] = bf16(in[k][n])   (LDS-tiled transpose, block (32,8))
// ---------------------------------------------------------------------------
__global__ __launch_bounds__(256) void transpose_cast(
    const float* __restrict__ in, unsigned short* __restrict__ out, int K, int N) {
  __shared__ float tile[32][33];
  int n0 = blockIdx.x * 32, k0 = blockIdx.y * 32;
  int tx = threadIdx.x, ty = threadIdx.y;
#pragma unroll
  for (int i = 0; i < 4; ++i)
    tile[ty + 8 * i][tx] = in[(size_t)(k0 + ty + 8 * i) * N + n0 + tx];
  __syncthreads();
#pragma unroll
  for (int i = 0; i < 4; ++i)
    out[(size_t)(n0 + ty + 8 * i) * K + k0 + tx] = f2bu(tile[tx][ty + 8 * i]);
}

// ---------------------------------------------------------------------------
// Shared GEMM mainloop: acc[4][4] += A[m0:128,K] @ Bt[n0:128,K]^T.
// 128x128 tile, 4 waves 2x2, BK=32, global_load_lds(16B), XOR chunk swizzle.
// ---------------------------------------------------------------------------
__device__ __forceinline__ void gemm_mainloop(
    const unsigned short* __restrict__ A, const unsigned short* __restrict__ Bt,
    int K, int m0, int n0, unsigned short* As, unsigned short* Bs,
    f32x4 acc[4][4]) {
  const int tid = threadIdx.x, lane = tid & 63, w = tid >> 6;
  const int l15 = lane & 15, quad = lane >> 4;
  const int wr = w >> 1, wc = w & 1;

  int rowS[2], colS[2];
#pragma unroll
  for (int i = 0; i < 2; ++i) {
    int f16 = (i * 4 + w) * 64 + lane;          // 0..511
    rowS[i] = f16 >> 2;                         // 4 chunks per 32-elem row
    colS[i] = ((f16 & 3) ^ (rowS[i] & 3)) * 8;  // element offset of k-chunk
  }
  const int swz = (quad ^ (l15 & 3)) * 16;      // reader: byte offset of chunk

  for (int kb = 0; kb < K; kb += 32) {
#pragma unroll
    for (int i = 0; i < 2; ++i) {
      gl_lds16(A + (size_t)(m0 + rowS[i]) * K + kb + colS[i],
               (char*)As + (size_t)((i * 4 + w) * 1024));
      gl_lds16(Bt + (size_t)(n0 + rowS[i]) * K + kb + colS[i],
               (char*)Bs + (size_t)((i * 4 + w) * 1024));
    }
    __syncthreads();  // drains vmcnt for global_load_lds
    bf16x8 aF[4], bF[4];
#pragma unroll
    for (int t = 0; t < 4; ++t) {
      aF[t] = *(const bf16x8*)((const char*)As + (wr * 64 + t * 16 + l15) * 64 + swz);
      bF[t] = *(const bf16x8*)((const char*)Bs + (wc * 64 + t * 16 + l15) * 64 + swz);
    }
#pragma unroll
    for (int mi = 0; mi < 4; ++mi)
#pragma unroll
      for (int ni = 0; ni < 4; ++ni)
        acc[mi][ni] = __builtin_amdgcn_mfma_f32_16x16x32_bf16(
            aF[mi], bF[ni], acc[mi][ni], 0, 0, 0);
    __syncthreads();
  }
}

// ---------------------------------------------------------------------------
// Generic C[M,N] = epi(A @ Bt^T + bias): relu flag, fp32/bf16 row-major out.
// ---------------------------------------------------------------------------
__global__ __launch_bounds__(256) void gemm_bt(
    const unsigned short* __restrict__ A, const unsigned short* __restrict__ Bt,
    const float* __restrict__ bias, void* __restrict__ Cout,
    int N, int K, float alpha, int relu, int ofp32) {
  __shared__ unsigned short As[128 * 32];
  __shared__ unsigned short Bs[128 * 32];
  const int tid = threadIdx.x, lane = tid & 63, w = tid >> 6;
  const int l15 = lane & 15, quad = lane >> 4;
  const int m0 = blockIdx.y * 128, n0 = blockIdx.x * 128;
  const int wr = w >> 1, wc = w & 1;

  f32x4 acc[4][4];
#pragma unroll
  for (int mi = 0; mi < 4; ++mi)
#pragma unroll
    for (int ni = 0; ni < 4; ++ni) acc[mi][ni] = {0.f, 0.f, 0.f, 0.f};

  gemm_mainloop(A, Bt, K, m0, n0, As, Bs, acc);

#pragma unroll
  for (int ni = 0; ni < 4; ++ni) {
    int col = n0 + wc * 64 + ni * 16 + l15;
    float bvv = bias[col];
#pragma unroll
    for (int mi = 0; mi < 4; ++mi) {
      int rbase = m0 + wr * 64 + mi * 16 + quad * 4;
#pragma unroll
      for (int r = 0; r < 4; ++r) {
        float val = alpha * (acc[mi][ni][r] + bvv);
        if (relu) val = fmaxf(val, 0.f);
        size_t idx = (size_t)(rbase + r) * N + col;
        if (ofp32) ((float*)Cout)[idx] = val;
        else ((unsigned short*)Cout)[idx] = f2bu(val);
      }
    }
  }
}

// ---------------------------------------------------------------------------
// Fused QKV gemm. N=3072 (region 0: Q *0.125 -> Qb rows; 1: K -> Kb rows;
// 2: V -> Vtg transposed per head [ (b*16+h)*64+d ][ s ]).
// ---------------------------------------------------------------------------
__global__ __launch_bounds__(256) void gemm_qkv(
    const unsigned short* __restrict__ A, const unsigned short* __restrict__ Bt,
    const float* __restrict__ bq, const float* __restrict__ bk,
    const float* __restrict__ bv,
    unsigned short* __restrict__ Qb, unsigned short* __restrict__ Kb,
    unsigned short* __restrict__ Vtg) {
  __shared__ unsigned short As[128 * 32];
  __shared__ unsigned short Bs[128 * 32];
  const int tid = threadIdx.x, lane = tid & 63, w = tid >> 6;
  const int l15 = lane & 15, quad = lane >> 4;
  const int m0 = blockIdx.y * 128, n0 = blockIdx.x * 128;
  const int wr = w >> 1, wc = w & 1;

  f32x4 acc[4][4];
#pragma unroll
  for (int mi = 0; mi < 4; ++mi)
#pragma unroll
    for (int ni = 0; ni < 4; ++ni) acc[mi][ni] = {0.f, 0.f, 0.f, 0.f};

  gemm_mainloop(A, Bt, DM, m0, n0, As, Bs, acc);

  const int region = n0 >> 10;        // 0=Q 1=K 2=V
  const int nloc0 = (n0 & 1023) + wc * 64;
  if (region < 2) {
    unsigned short* Out = region ? Kb : Qb;
    const float* bias = region ? bk : bq;
    const float alpha = region ? 1.0f : 0.125f;  // fold 1/sqrt(64) into Q
#pragma unroll
    for (int ni = 0; ni < 4; ++ni) {
      int col = nloc0 + ni * 16 + l15;
      float bvv = bias[col];
#pragma unroll
      for (int mi = 0; mi < 4; ++mi) {
        int rbase = m0 + wr * 64 + mi * 16 + quad * 4;
#pragma unroll
        for (int r = 0; r < 4; ++r)
          Out[(size_t)(rbase + r) * DM + col] = f2bu(alpha * (acc[mi][ni][r] + bvv));
      }
    }
  } else {
#pragma unroll
    for (int ni = 0; ni < 4; ++ni) {
      int col = nloc0 + ni * 16 + l15;       // d_model index of V
      float bvv = bv[col];
      int hh = col >> 6, dl = col & 63;
#pragma unroll
      for (int mi = 0; mi < 4; ++mi) {
        int rbase = m0 + wr * 64 + mi * 16 + quad * 4;
        int b_ = rbase >> 11, s0 = rbase & 2047;  // s0 multiple of 4
        u16x4 pk;
#pragma unroll
        for (int r = 0; r < 4; ++r) pk[r] = f2bu(acc[mi][ni][r] + bvv);
        *(u16x4*)(Vtg + ((size_t)((b_ * NH + hh) * HD + dl)) * SEQ + s0) = pk;
      }
    }
  }
}

// ---------------------------------------------------------------------------
// Flash attention, S^T formulation. grid=(SEQ/64, BATCH*NH), block=256.
// Each wave: 16 q rows (in regs), 64 kv per j step.
// S^T = K Q^T  (A=Kt rows kv, B=Q regs rows q) -> C col = q = l15:
//   softmax reduce = 15 in-reg ops + 2 shfl; P packs to ds_write_b64.
// O = P V      (A=Pt rows q, B=Vt rows d [from pre-transposed Vtg]).
// LDS ~25KB -> 4+ blocks/CU.
// ---------------------------------------------------------------------------
__global__ __launch_bounds__(256) void attn_kernel(
    const unsigned short* __restrict__ Q, const unsigned short* __restrict__ K,
    const unsigned short* __restrict__ Vtg, unsigned short* __restrict__ O) {
  __shared__ unsigned short Kt[64 * 64];      // [kv][d] swizzled, 8KB
  __shared__ unsigned short Vt[64 * 64];      // [d][kv] swizzled, 8KB
  __shared__ unsigned short Pt[4][16 * 64];   // per-wave [q][kv], 8KB
  __shared__ __align__(16) float redA[4][16];
  __shared__ __align__(16) float redL[4][16];

  const int tid = threadIdx.x, lane = tid & 63, w = tid >> 6;
  const int l15 = lane & 15, quad = lane >> 4;
  const int q0 = blockIdx.x * 64;
  const int bh = blockIdx.y, b = bh >> 4, hh = bh & 15;
  const size_t tokbase = (size_t)b * SEQ;

  // Q fragment in registers, reused all j: rows q = q0 + w*16 + l15
  bf16x8 qf[2];
#pragma unroll
  for (int kk = 0; kk < 2; ++kk)
    qf[kk] = *(const bf16x8*)(Q + (tokbase + q0 + w * 16 + l15) * DM + hh * HD +
                              kk * 32 + quad * 8);

  float m_run = -3.0e38f, l_run = 0.f;
  f32x4 Oacc[4];
#pragma unroll
  for (int nt = 0; nt < 4; ++nt) Oacc[nt] = {0.f, 0.f, 0.f, 0.f};

  char* ptw = (char*)&Pt[w][0];

  for (int j = 0; j < SEQ / 64; ++j) {
    const int kv0 = j * 64;
    __syncthreads();  // prior consumers of Kt/Vt done
    // stage Kt [64 kv][64 d] and Vt [64 d][64 kv], 512 chunks each
#pragma unroll
    for (int i = 0; i < 2; ++i) {
      int f = (i * 4 + w) * 64 + lane;
      int row = f >> 3, csrc = (f & 7) ^ (row & 7);
      gl_lds16(K + (tokbase + kv0 + row) * DM + hh * HD + csrc * 8,
               (char*)Kt + (size_t)(i * 4 + w) * 1024);
      gl_lds16(Vtg + ((size_t)bh * HD + row) * SEQ + kv0 + csrc * 8,
               (char*)Vt + (size_t)(i * 4 + w) * 1024);
    }
    __syncthreads();

    // ---- S^T = K Q^T : C[kv][q], col q = l15 ----
    f32x4 S[4];
#pragma unroll
    for (int mt = 0; mt < 4; ++mt) S[mt] = {0.f, 0.f, 0.f, 0.f};
#pragma unroll
    for (int kk = 0; kk < 2; ++kk) {
#pragma unroll
      for (int mt = 0; mt < 4; ++mt) {
        int row = mt * 16 + l15;
        bf16x8 aK = *(const bf16x8*)((const char*)Kt + row * 128 +
                                     (((kk * 4 + quad) ^ (row & 7)) * 16));
        S[mt] = __builtin_amdgcn_mfma_f32_16x16x32_bf16(aK, qf[kk], S[mt], 0, 0, 0);
      }
    }

    // ---- online softmax: lane owns column q = l15 ----
    float mx = S[0][0];
#pragma unroll
    for (int mt = 0; mt < 4; ++mt)
#pragma unroll
      for (int r = 0; r < 4; ++r) mx = fmaxf(mx, S[mt][r]);
    mx = fmaxf(mx, __shfl_xor(mx, 16));
    mx = fmaxf(mx, __shfl_xor(mx, 32));
    float mn = fmaxf(m_run, mx);
    float al = __expf(m_run - mn);
    m_run = mn;
    float rs = 0.f;
#pragma unroll
    for (int mt = 0; mt < 4; ++mt) {
      u16x4 pk;
#pragma unroll
      for (int r = 0; r < 4; ++r) {
        float p = __expf(S[mt][r] - mn);
        rs += p;
        pk[r] = f2bu(p);
      }
      // P[q=l15][kv = mt*16+quad*4+r]: chunk c = mt*2+(quad>>1), ^ (q&7)
      *(u16x4*)(ptw + l15 * 128 +
                (((mt * 2 + (quad >> 1)) ^ (l15 & 7)) * 16 + (quad & 1) * 8)) = pk;
    }
    rs += __shfl_xor(rs, 16);
    rs += __shfl_xor(rs, 32);
    l_run = l_run * al + rs;
    if (lane < 16) redA[w][lane] = al;
    // rescale Oacc rows q = quad*4+r  (same-wave LDS write->read, in-order)
    f32x4 alv = *(const f32x4*)&redA[w][quad * 4];
#pragma unroll
    for (int nt = 0; nt < 4; ++nt) Oacc[nt] *= alv;

    // ---- O += P V : A=Pt rows q, B=Vt rows d ----
#pragma unroll
    for (int kk = 0; kk < 2; ++kk) {
      bf16x8 aP = *(const bf16x8*)(ptw + l15 * 128 +
                                   (((kk * 4 + quad) ^ (l15 & 7)) * 16));
#pragma unroll
      for (int nt = 0; nt < 4; ++nt) {
        int row = nt * 16 + l15;
        bf16x8 bV = *(const bf16x8*)((const char*)Vt + row * 128 +
                                     (((kk * 4 + quad) ^ (row & 7)) * 16));
        Oacc[nt] = __builtin_amdgcn_mfma_f32_16x16x32_bf16(aP, bV, Oacc[nt], 0, 0, 0);
      }
    }
  }

  // epilogue: O rows q = q0 + w*16 + quad*4 + r, cols d = nt*16 + l15
  if (lane < 16) redL[w][lane] = l_run;
  f32x4 lv = *(const f32x4*)&redL[w][quad * 4];
  f32x4 li;
#pragma unroll
  for (int r = 0; r < 4; ++r) li[r] = 1.0f / lv[r];
#pragma unroll
  for (int nt = 0; nt < 4; ++nt)
#pragma unroll
    for (int r = 0; r < 4; ++r) {
      size_t tok = tokbase + q0 + w * 16 + quad * 4 + r;
      O[tok * DM + hh * HD + nt * 16 + l15] = f2bu(Oacc[nt][r] * li[r]);
    }
}

// ---------------------------------------------------------------------------
// row-wise: s = base + delta; LN(s)*gamma+beta -> outf (fp32), outb (bf16 opt)
// ---------------------------------------------------------------------------
__global__ __launch_bounds__(256) void ln_res(
    const float* __restrict__ base, const float* __restrict__ delta,
    const float* __restrict__ gamma, const float* __restrict__ beta,
    float* __restrict__ outf, unsigned short* __restrict__ outb) {
  __shared__ float red[8];
  const int row = blockIdx.x, tid = threadIdx.x;
  const size_t rb = (size_t)row * DM;
  float4 xv = ((const float4*)(base + rb))[tid];
  float4 dv = ((const float4*)(delta + rb))[tid];
  float s0 = xv.x + dv.x, s1 = xv.y + dv.y, s2 = xv.z + dv.z, s3 = xv.w + dv.w;
  float t = s0 + s1 + s2 + s3;
#pragma unroll
  for (int m = 1; m < 64; m <<= 1) t += __shfl_xor(t, m);
  if ((tid & 63) == 0) red[tid >> 6] = t;
  __syncthreads();
  float mu = (red[0] + red[1] + red[2] + red[3]) * (1.0f / DM);
  float d0 = s0 - mu, d1 = s1 - mu, d2 = s2 - mu, d3 = s3 - mu;
  float v = d0 * d0 + d1 * d1 + d2 * d2 + d3 * d3;
#pragma unroll
  for (int m = 1; m < 64; m <<= 1) v += __shfl_xor(v, m);
  if ((tid & 63) == 0) red[4 + (tid >> 6)] = v;
  __syncthreads();
  float var = (red[4] + red[5] + red[6] + red[7]) * (1.0f / DM);
  float rs = rsqrtf(var + 1e-5f);
  float4 gv = ((const float4*)gamma)[tid];
  float4 bv = ((const float4*)beta)[tid];
  float o0 = d0 * rs * gv.x + bv.x;
  float o1 = d1 * rs * gv.y + bv.y;
  float o2 = d2 * rs * gv.z + bv.z;
  float o3 = d3 * rs * gv.w + bv.w;
  float4 ov = {o0, o1, o2, o3};
  ((float4*)(outf + rb))[tid] = ov;
  if (outb) {
    u16x4 ob = {f2bu(o0), f2bu(o1), f2bu(o2), f2bu(o3)};
    ((u16x4*)(outb + rb))[tid] = ob;
  }
}

// ---------------------------------------------------------------------------
extern "C" void kernel_launch(void* const* d_in, const int* in_sizes, int n_in,
                              void* d_out, int out_size, void* d_ws, size_t ws_size,
                              hipStream_t stream) {
  const float* x   = (const float*)d_in[0];
  const float* Wq  = (const float*)d_in[1];  const float* bq  = (const float*)d_in[2];
  const float* Wk  = (const float*)d_in[3];  const float* bk  = (const float*)d_in[4];
  const float* Wv  = (const float*)d_in[5];  const float* bvv = (const float*)d_in[6];
  const float* Wo  = (const float*)d_in[7];  const float* bo  = (const float*)d_in[8];
  const float* W1  = (const float*)d_in[9];  const float* b1  = (const float*)d_in[10];
  const float* W2  = (const float*)d_in[11]; const float* b2  = (const float*)d_in[12];
  const float* g1  = (const float*)d_in[13]; const float* be1 = (const float*)d_in[14];
  const float* g2  = (const float*)d_in[15]; const float* be2 = (const float*)d_in[16];

  char* ws = (char*)d_ws;
  const size_t MB = 1ull << 20;
  unsigned short* xb    = (unsigned short*)(ws + 0 * MB);    // 16MB (later hb alias)
  unsigned short* wqkvT = (unsigned short*)(ws + 16 * MB);   // 6MB  [3072][1024]
  unsigned short* woT   = (unsigned short*)(ws + 22 * MB);   // 2MB
  unsigned short* w1T   = (unsigned short*)(ws + 24 * MB);   // 8MB
  unsigned short* w2T   = (unsigned short*)(ws + 32 * MB);   // 8MB
  unsigned short* Qb    = (unsigned short*)(ws + 40 * MB);   // 16MB
  unsigned short* Kb    = (unsigned short*)(ws + 56 * MB);   // 16MB
  unsigned short* Vtg   = (unsigned short*)(ws + 72 * MB);   // 32MB [(b,h,d)][s]
  unsigned short* aO    = (unsigned short*)(ws + 104 * MB);  // 16MB
  float*          prj   = (float*)(ws + 120 * MB);           // 32MB fp32
  float*          h     = (float*)(ws + 152 * MB);           // 32MB fp32
  unsigned short* hb    = (unsigned short*)(ws + 0 * MB);    // alias xb (dead)
  unsigned short* ffm   = (unsigned short*)(ws + 40 * MB);   // 64MB alias Qb..Vtg
  float*          ffo   = (float*)(ws + 104 * MB);           // 32MB alias aO+prj
  (void)ws_size; (void)in_sizes; (void)n_in; (void)out_size;

  // prep: casts + weight transposes (B^T bf16); Wq/Wk/Wv stacked -> wqkvT
  cast_bf16<<<TOK * DM / 4 / 256, 256, 0, stream>>>(x, xb, TOK * DM / 4);
  transpose_cast<<<dim3(DM / 32, DM / 32), dim3(32, 8), 0, stream>>>(Wq, wqkvT, DM, DM);
  transpose_cast<<<dim3(DM / 32, DM / 32), dim3(32, 8), 0, stream>>>(Wk, wqkvT + 1024 * 1024, DM, DM);
  transpose_cast<<<dim3(DM / 32, DM / 32), dim3(32, 8), 0, stream>>>(Wv, wqkvT + 2048 * 1024, DM, DM);
  transpose_cast<<<dim3(DM / 32, DM / 32), dim3(32, 8), 0, stream>>>(Wo, woT, DM, DM);
  transpose_cast<<<dim3(DFF / 32, DM / 32), dim3(32, 8), 0, stream>>>(W1, w1T, DM, DFF);
  transpose_cast<<<dim3(DM / 32, DFF / 32), dim3(32, 8), 0, stream>>>(W2, w2T, DFF, DM);

  // fused QKV projection (Q scaled 0.125; V written transposed per head)
  gemm_qkv<<<dim3(3 * DM / 128, TOK / 128), 256, 0, stream>>>(
      xb, wqkvT, bq, bk, bvv, Qb, Kb, Vtg);

  // attention
  attn_kernel<<<dim3(SEQ / 64, BATCH * NH), 256, 0, stream>>>(Qb, Kb, Vtg, aO);

  // output projection (fp32 out for residual precision)
  gemm_bt<<<dim3(DM / 128, TOK / 128), 256, 0, stream>>>(aO, woT, bo, prj, DM, DM, 1.0f, 0, 1);
  // LN1: h = LN(x + prj) -> fp32 h + bf16 hb
  ln_res<<<TOK, 256, 0, stream>>>(x, prj, g1, be1, h, hb);

  // FF
  gemm_bt<<<dim3(DFF / 128, TOK / 128), 256, 0, stream>>>(hb, w1T, b1, ffm, DFF, DM, 1.0f, 1, 0);
  gemm_bt<<<dim3(DM / 128, TOK / 128), 256, 0, stream>>>(ffm, w2T, b2, ffo, DM, DFF, 1.0f, 0, 1);

  // LN2 -> d_out (fp32)
  ln_res<<<TOK, 256, 0, stream>>>(h, ffo, g2, be2, (float*)d_out, nullptr);
}